// Round 1
// baseline (1341.223 us; speedup 1.0000x reference)
//
#include <hip/hip_runtime.h>
#include <math.h>

#define NSEQ 4096
#define LOG2E 1.4426950408889634f
#define ATT_SCALE 0.17677669529663687f  // 32^-0.5

// ---------------------------------------------------------------------------
// Y[b][m][n] = sum_k W[m][k] * X[b][k][n] + bias[m]
// grid: (N/64, M/64, B), block 256. K multiple of 64, N multiple of 64.
// ---------------------------------------------------------------------------
__global__ __launch_bounds__(256) void gemm_bias(
    const float* __restrict__ W, const float* __restrict__ X,
    const float* __restrict__ bias, float* __restrict__ Y,
    int M, int K, int N) {
  __shared__ float As[64][68];  // [k][m] (transposed on store)
  __shared__ float Bs[64][68];  // [k][n]
  const int b = blockIdx.z;
  const int n0 = blockIdx.x * 64, m0 = blockIdx.y * 64;
  const float* Xb = X + (size_t)b * K * N;
  const int tid = threadIdx.x;
  const int tx = tid & 15, ty = tid >> 4;
  float acc[4][4] = {};
  for (int k0 = 0; k0 < K; k0 += 64) {
    #pragma unroll
    for (int i = 0; i < 4; ++i) {
      const int r = ty + 16 * i;  // reuse ty as row-group, tx as float4-col
      float4 w4 = *(const float4*)(W + (size_t)(m0 + r) * K + k0 + tx * 4);
      As[tx * 4 + 0][r] = w4.x;
      As[tx * 4 + 1][r] = w4.y;
      As[tx * 4 + 2][r] = w4.z;
      As[tx * 4 + 3][r] = w4.w;
      float4 x4 = *(const float4*)(Xb + (size_t)(k0 + r) * N + n0 + tx * 4);
      *(float4*)&Bs[r][tx * 4] = x4;
    }
    __syncthreads();
    #pragma unroll 8
    for (int kk = 0; kk < 64; ++kk) {
      float4 a4 = *(const float4*)&As[kk][ty * 4];
      float4 b4 = *(const float4*)&Bs[kk][tx * 4];
      const float av[4] = {a4.x, a4.y, a4.z, a4.w};
      const float bv[4] = {b4.x, b4.y, b4.z, b4.w};
      #pragma unroll
      for (int i = 0; i < 4; ++i)
        #pragma unroll
        for (int jj = 0; jj < 4; ++jj)
          acc[i][jj] = fmaf(av[i], bv[jj], acc[i][jj]);
    }
    __syncthreads();
  }
  #pragma unroll
  for (int i = 0; i < 4; ++i) {
    const float bi = bias[m0 + ty * 4 + i];
    float4 o;
    o.x = acc[i][0] + bi;
    o.y = acc[i][1] + bi;
    o.z = acc[i][2] + bi;
    o.w = acc[i][3] + bi;
    *(float4*)(Y + ((size_t)b * M + m0 + ty * 4 + i) * N + n0 + tx * 4) = o;
  }
}

// ---------------------------------------------------------------------------
// Flash attention, fp32. qkv layout: [b][768][N] with channel o = s*256+h*32+d.
// grid: (N/64, H, B), block 256 = 4 waves. Each lane owns ONE query row
// (n0+lane); each wave processes a 1024-key slice (keys split 4-way across
// waves), K/V tiles broadcast-read from a private LDS slice. Partial
// (m,l,acc) merged through LDS at the end.
// ao layout: [b][256][N] with channel c = h*32+d.
// ---------------------------------------------------------------------------
__global__ __launch_bounds__(256) void flash_attn(
    const float* __restrict__ qkv, float* __restrict__ ao) {
  __shared__ float smem[8704];  // 4 waves * 2048 (K+V tiles) ; reused as 4*34*64 partials
  const int b = blockIdx.z, h = blockIdx.y;
  const int n0 = blockIdx.x * 64;
  const int tid = threadIdx.x;
  const int w = tid >> 6, lane = tid & 63;
  const float* Qb = qkv + ((size_t)b * 768 + h * 32) * NSEQ;
  const float* Kb = qkv + ((size_t)b * 768 + 256 + h * 32) * NSEQ;
  const float* Vb = qkv + ((size_t)b * 768 + 512 + h * 32) * NSEQ;

  float q[32], acc[32];
  #pragma unroll
  for (int d = 0; d < 32; ++d) {
    q[d] = Qb[(size_t)d * NSEQ + n0 + lane] * ATT_SCALE;  // coalesced per d
    acc[d] = 0.f;
  }
  float m = -INFINITY, l = 0.f;
  float* kv = smem + w * 2048;  // K[32][32] then V[32][32], layout [d][key]

  for (int t = 0; t < 32; ++t) {
    const int key0 = w * 1024 + t * 32;
    // stage K,V tile (wave-private slice; no barrier needed)
    #pragma unroll
    for (int c = 0; c < 4; ++c) {
      const int d = c * 8 + (lane >> 3);
      const int col = (lane & 7) * 4;
      float4 kq = *(const float4*)(Kb + (size_t)d * NSEQ + key0 + col);
      float4 vq = *(const float4*)(Vb + (size_t)d * NSEQ + key0 + col);
      *(float4*)(kv + c * 256 + lane * 4) = kq;
      *(float4*)(kv + 1024 + c * 256 + lane * 4) = vq;
    }
    // scores: s[j] = q . K[:,key0+j]  (all lanes read same LDS addr -> broadcast)
    float s[32];
    #pragma unroll
    for (int jj = 0; jj < 32; ++jj) s[jj] = 0.f;
    #pragma unroll
    for (int d = 0; d < 32; ++d) {
      const float qd = q[d];
      const float4* kr = (const float4*)(kv + d * 32);
      #pragma unroll
      for (int j4 = 0; j4 < 8; ++j4) {
        float4 k4 = kr[j4];
        s[j4 * 4 + 0] = fmaf(qd, k4.x, s[j4 * 4 + 0]);
        s[j4 * 4 + 1] = fmaf(qd, k4.y, s[j4 * 4 + 1]);
        s[j4 * 4 + 2] = fmaf(qd, k4.z, s[j4 * 4 + 2]);
        s[j4 * 4 + 3] = fmaf(qd, k4.w, s[j4 * 4 + 3]);
      }
    }
    // online softmax, fully lane-local
    float mx = s[0];
    #pragma unroll
    for (int jj = 1; jj < 32; ++jj) mx = fmaxf(mx, s[jj]);
    const float mnew = fmaxf(m, mx);
    const float rsc = exp2f((m - mnew) * LOG2E);
    m = mnew;
    l *= rsc;
    #pragma unroll
    for (int d = 0; d < 32; ++d) acc[d] *= rsc;
    float ps = 0.f;
    #pragma unroll
    for (int jj = 0; jj < 32; ++jj) {
      s[jj] = exp2f((s[jj] - mnew) * LOG2E);
      ps += s[jj];
    }
    l += ps;
    // PV: acc[d] += sum_j s[j] * V[d][key0+j]
    #pragma unroll
    for (int d = 0; d < 32; ++d) {
      const float4* vr = (const float4*)(kv + 1024 + d * 32);
      float a = acc[d];
      #pragma unroll
      for (int j4 = 0; j4 < 8; ++j4) {
        float4 v4 = vr[j4];
        a = fmaf(s[j4 * 4 + 0], v4.x, a);
        a = fmaf(s[j4 * 4 + 1], v4.y, a);
        a = fmaf(s[j4 * 4 + 2], v4.z, a);
        a = fmaf(s[j4 * 4 + 3], v4.w, a);
      }
      acc[d] = a;
    }
  }

  // merge the 4 key-split partials via LDS
  __syncthreads();  // everyone done reading K/V slices
  float* P = smem;  // layout: P[w][34][64]  (m, l, acc[0..31]) x 64 rows
  P[(w * 34 + 0) * 64 + lane] = m;
  P[(w * 34 + 1) * 64 + lane] = l;
  #pragma unroll
  for (int d = 0; d < 32; ++d) P[(w * 34 + 2 + d) * 64 + lane] = acc[d];
  __syncthreads();

  const int r = tid & 63, dg = tid >> 6;  // thread -> (row, d-group of 8)
  float mw[4], lw[4], sc[4];
  #pragma unroll
  for (int w2 = 0; w2 < 4; ++w2) {
    mw[w2] = P[(w2 * 34 + 0) * 64 + r];
    lw[w2] = P[(w2 * 34 + 1) * 64 + r];
  }
  const float Mg = fmaxf(fmaxf(mw[0], mw[1]), fmaxf(mw[2], mw[3]));
  float L = 0.f;
  #pragma unroll
  for (int w2 = 0; w2 < 4; ++w2) {
    sc[w2] = exp2f((mw[w2] - Mg) * LOG2E);
    L += lw[w2] * sc[w2];
  }
  const float inv = 1.f / L;
  #pragma unroll
  for (int jj = 0; jj < 8; ++jj) {
    const int d = dg * 8 + jj;
    float o = 0.f;
    #pragma unroll
    for (int w2 = 0; w2 < 4; ++w2) o += P[(w2 * 34 + 2 + d) * 64 + r] * sc[w2];
    ao[((size_t)b * 256 + h * 32 + d) * NSEQ + n0 + r] = o * inv;  // coalesced over r
  }
}

// ---------------------------------------------------------------------------
extern "C" void kernel_launch(void* const* d_in, const int* in_sizes, int n_in,
                              void* d_out, int out_size, void* d_ws, size_t ws_size,
                              hipStream_t stream) {
  const float* x = (const float*)d_in[0];       // [2][256][4096]
  const float* qkv_w = (const float*)d_in[1];   // [768][256]
  const float* qkv_b = (const float*)d_in[2];   // [768]
  const float* out_w = (const float*)d_in[3];   // [256][256]
  const float* out_b = (const float*)d_in[4];   // [256]
  float* out = (float*)d_out;                   // [2][256][4096]

  float* qkv = (float*)d_ws;                    // [2][768][4096] fp32 (24 MB)
  float* ao = qkv + (size_t)2 * 768 * NSEQ;     // [2][256][4096] fp32 (8 MB)

  // qkv = qkv_w @ x + qkv_b
  gemm_bias<<<dim3(NSEQ / 64, 768 / 64, 2), 256, 0, stream>>>(
      qkv_w, x, qkv_b, qkv, 768, 256, NSEQ);
  // flash attention per (b,h), 64 query rows per block
  flash_attn<<<dim3(NSEQ / 64, 8, 2), 256, 0, stream>>>(qkv, ao);
  // out = out_w @ ao + out_b
  gemm_bias<<<dim3(NSEQ / 64, 256 / 64, 2), 256, 0, stream>>>(
      out_w, ao, out_b, out, 256, 256, NSEQ);
}

// Round 2
// 350.925 us; speedup vs baseline: 3.8220x; 3.8220x over previous
//
#include <hip/hip_runtime.h>
#include <math.h>

#define NSEQ 4096
#define ATT_SCALE 0.17677669529663687f                 // 32^-0.5
#define QSC (ATT_SCALE * 1.4426950408889634f)          // fold log2(e) into Q

typedef __attribute__((ext_vector_type(8))) short bf16x8;
typedef __attribute__((ext_vector_type(4))) float f32x4;
typedef __attribute__((ext_vector_type(2))) unsigned int u32x2;

__device__ __forceinline__ unsigned short f2bf(float f) {
  unsigned u = __builtin_bit_cast(unsigned, f);
  u += 0x7fffu + ((u >> 16) & 1u);
  return (unsigned short)(u >> 16);
}
__device__ __forceinline__ float bf2f(unsigned short h) {
  unsigned u = ((unsigned)h) << 16;
  return __builtin_bit_cast(float, u);
}

// ---------------------------------------------------------------------------
// Y[b][m][n] = sum_k W[m][k] * X[b][k][n] + bias[m]   (fp32 VALU tile GEMM)
// X b-stride = xbstride elements; Y row index uses ybstride rows per batch.
// If Vh != nullptr and m0 >= 512: rows are V channels -> write bf16 hi/lo
// planes [bh][d][n] instead of fp32 Y.
// ---------------------------------------------------------------------------
__global__ __launch_bounds__(256) void gemm_bias(
    const float* __restrict__ W, const float* __restrict__ X,
    const float* __restrict__ bias, float* __restrict__ Y,
    int M, int K, int N, size_t xbstride, int ybstride,
    unsigned short* __restrict__ Vh, unsigned short* __restrict__ Vl) {
  __shared__ float As[64][68];  // [k][m]
  __shared__ float Bs[64][68];  // [k][n]
  const int b = blockIdx.z;
  const int n0 = blockIdx.x * 64, m0 = blockIdx.y * 64;
  const float* Xb = X + (size_t)b * xbstride;
  const int tid = threadIdx.x;
  const int tx = tid & 15, ty = tid >> 4;
  float acc[4][4] = {};
  for (int k0 = 0; k0 < K; k0 += 64) {
    #pragma unroll
    for (int i = 0; i < 4; ++i) {
      const int r = ty + 16 * i;
      float4 w4 = *(const float4*)(W + (size_t)(m0 + r) * K + k0 + tx * 4);
      As[tx * 4 + 0][r] = w4.x;
      As[tx * 4 + 1][r] = w4.y;
      As[tx * 4 + 2][r] = w4.z;
      As[tx * 4 + 3][r] = w4.w;
      float4 x4 = *(const float4*)(Xb + (size_t)(k0 + r) * N + n0 + tx * 4);
      *(float4*)&Bs[r][tx * 4] = x4;
    }
    __syncthreads();
    #pragma unroll 8
    for (int kk = 0; kk < 64; ++kk) {
      float4 a4 = *(const float4*)&As[kk][ty * 4];
      float4 b4 = *(const float4*)&Bs[kk][tx * 4];
      const float av[4] = {a4.x, a4.y, a4.z, a4.w};
      const float bv[4] = {b4.x, b4.y, b4.z, b4.w};
      #pragma unroll
      for (int i = 0; i < 4; ++i)
        #pragma unroll
        for (int jj = 0; jj < 4; ++jj)
          acc[i][jj] = fmaf(av[i], bv[jj], acc[i][jj]);
    }
    __syncthreads();
  }
  if (Vh != nullptr && m0 >= 512) {
    // V rows: split to bf16 hi/lo planes, layout [bh][d][n]
    #pragma unroll
    for (int i = 0; i < 4; ++i) {
      const int o = m0 + ty * 4 + i;
      const float bi = bias[o];
      const int d = o & 31, hh = (o >> 5) - 16;
      unsigned hw[2] = {0u, 0u}, lw[2] = {0u, 0u};
      #pragma unroll
      for (int jj = 0; jj < 4; ++jj) {
        float v = acc[i][jj] + bi;
        unsigned short hv = f2bf(v);
        unsigned short lv = f2bf(v - bf2f(hv));
        hw[jj >> 1] |= ((unsigned)hv) << (16 * (jj & 1));
        lw[jj >> 1] |= ((unsigned)lv) << (16 * (jj & 1));
      }
      const size_t base = (((size_t)(b * 8 + hh)) * 32 + d) * N + n0 + tx * 4;
      u32x2 H, L;
      H[0] = hw[0]; H[1] = hw[1];
      L[0] = lw[0]; L[1] = lw[1];
      *(u32x2*)(Vh + base) = H;
      *(u32x2*)(Vl + base) = L;
    }
  } else {
    #pragma unroll
    for (int i = 0; i < 4; ++i) {
      const float bi = bias[m0 + ty * 4 + i];
      float4 o;
      o.x = acc[i][0] + bi;
      o.y = acc[i][1] + bi;
      o.z = acc[i][2] + bi;
      o.w = acc[i][3] + bi;
      *(float4*)(Y + ((size_t)b * ybstride + m0 + ty * 4 + i) * N + n0 + tx * 4) = o;
    }
  }
}

// ---------------------------------------------------------------------------
// K prep: transpose-split fp32 qkv K channels [b][256+hw*32+d][n] into bf16
// hi/lo planes [bh][n][32d]. grid (N/64, 16), 256 thr.
// ---------------------------------------------------------------------------
__global__ __launch_bounds__(256) void prep_k(
    const float* __restrict__ qkvf, unsigned short* __restrict__ Kh,
    unsigned short* __restrict__ Kl) {
  const int bh = blockIdx.y, b = bh >> 3, hh = bh & 7;
  const int n0 = blockIdx.x * 64;
  const int t = threadIdx.x;
  const int n = t >> 2, dg = t & 3;
  const float* src = qkvf + ((size_t)b * 512 + 256 + hh * 32 + 8 * dg) * NSEQ + n0 + n;
  bf16x8 hi, lo;
  #pragma unroll
  for (int i = 0; i < 8; ++i) {
    float v = src[(size_t)i * NSEQ];
    unsigned short hv = f2bf(v);
    hi[i] = (short)hv;
    lo[i] = (short)f2bf(v - bf2f(hv));
  }
  const size_t dst = ((size_t)bh * NSEQ + n0 + n) * 32 + 8 * dg;
  *(bf16x8*)(Kh + dst) = hi;
  *(bf16x8*)(Kl + dst) = lo;
}

// ---------------------------------------------------------------------------
// MFMA flash attention, bf16x3 error-compensated.
// Q read fp32 from qkvf [b][h*32+d][n] (scaled by ATT_SCALE*log2e, split).
// K planes [bh][n][32d]; V planes [bh][32d][n]. Swapped QK: S^T = K*Q^T so
// online softmax is 2 shfl_xor; PV as O^T = V^T * P^T (P via swizzled LDS
// round-trip, wave-private). 4 waves x 32 queries = 128 q/block.
// ao (= qkvf Q region, per-block write-after-read safe): [b][h*32+d][n].
// ---------------------------------------------------------------------------
__global__ __launch_bounds__(256) void attn_mfma(
    const float* __restrict__ qkvf,
    const unsigned short* __restrict__ Kh, const unsigned short* __restrict__ Kl,
    const unsigned short* __restrict__ Vh, const unsigned short* __restrict__ Vl,
    float* __restrict__ ao) {
  __shared__ unsigned short P_lds[4][2][32][64];  // [wave][plane][q][k], rows 128B, XOR-swizzled
  const int b = blockIdx.z, h = blockIdx.y, bh = b * 8 + h;
  const int tid = threadIdx.x, w = tid >> 6, lane = tid & 63;
  const int lq = lane & 15, g = lane >> 4;
  const int n0 = blockIdx.x * 128 + w * 32;  // wave's query base
  const int sw = (lq & 7) << 4;              // LDS byte swizzle

  // Q fragments (one-time scattered fp32 read, scale+split in regs)
  bf16x8 qh[2], ql[2];
  #pragma unroll
  for (int qs = 0; qs < 2; ++qs) {
    const float* Qp = qkvf + ((size_t)b * 512 + h * 32 + 8 * g) * NSEQ + n0 + qs * 16 + lq;
    #pragma unroll
    for (int i = 0; i < 8; ++i) {
      float v = Qp[(size_t)i * NSEQ] * QSC;
      unsigned short hv = f2bf(v);
      qh[qs][i] = (short)hv;
      ql[qs][i] = (short)f2bf(v - bf2f(hv));
    }
  }
  f32x4 acc[2][2] = {};                    // [dsub][qsub] O^T tiles
  float m_[2] = {-1e30f, -1e30f}, l_[2] = {0.f, 0.f};
  char* PhB = (char*)&P_lds[w][0][0][0];
  char* PlB = (char*)&P_lds[w][1][0][0];
  const size_t kbase = (size_t)bh * NSEQ * 32;
  const size_t vbase = (size_t)bh * 32 * NSEQ;

  for (int t = 0; t < NSEQ / 64; ++t) {
    const int key0 = t * 64;
    float p[2][16];  // [qsub][ksub*4+r]  scores in log2 domain
    // ---- S^T = K * Q^T (3-term split) ----
    #pragma unroll
    for (int ks = 0; ks < 4; ++ks) {
      const size_t ko = kbase + (size_t)(key0 + ks * 16 + lq) * 32 + 8 * g;
      bf16x8 kfh = *(const bf16x8*)(Kh + ko);
      bf16x8 kfl = *(const bf16x8*)(Kl + ko);
      #pragma unroll
      for (int qs = 0; qs < 2; ++qs) {
        f32x4 c = {0.f, 0.f, 0.f, 0.f};
        c = __builtin_amdgcn_mfma_f32_16x16x32_bf16(kfh, qh[qs], c, 0, 0, 0);
        c = __builtin_amdgcn_mfma_f32_16x16x32_bf16(kfl, qh[qs], c, 0, 0, 0);
        c = __builtin_amdgcn_mfma_f32_16x16x32_bf16(kfh, ql[qs], c, 0, 0, 0);
        #pragma unroll
        for (int r = 0; r < 4; ++r) p[qs][ks * 4 + r] = c[r];
      }
    }
    // ---- online softmax (lane-local + 2 shfl) + P split to LDS ----
    #pragma unroll
    for (int qs = 0; qs < 2; ++qs) {
      float mt = p[qs][0];
      #pragma unroll
      for (int i = 1; i < 16; ++i) mt = fmaxf(mt, p[qs][i]);
      mt = fmaxf(mt, __shfl_xor(mt, 16));
      mt = fmaxf(mt, __shfl_xor(mt, 32));
      const float mn = fmaxf(m_[qs], mt);
      const float rs = exp2f(m_[qs] - mn);
      m_[qs] = mn;
      float ps = 0.f;
      #pragma unroll
      for (int i = 0; i < 16; ++i) {
        p[qs][i] = exp2f(p[qs][i] - mn);
        ps += p[qs][i];
      }
      ps += __shfl_xor(ps, 16);
      ps += __shfl_xor(ps, 32);
      l_[qs] = l_[qs] * rs + ps;
      acc[0][qs] *= rs;
      acc[1][qs] *= rs;
      const int row = qs * 16 + lq;
      #pragma unroll
      for (int ks = 0; ks < 4; ++ks) {
        unsigned short h0 = f2bf(p[qs][ks * 4 + 0]);
        unsigned short h1 = f2bf(p[qs][ks * 4 + 1]);
        unsigned short h2 = f2bf(p[qs][ks * 4 + 2]);
        unsigned short h3 = f2bf(p[qs][ks * 4 + 3]);
        unsigned short e0 = f2bf(p[qs][ks * 4 + 0] - bf2f(h0));
        unsigned short e1 = f2bf(p[qs][ks * 4 + 1] - bf2f(h1));
        unsigned short e2 = f2bf(p[qs][ks * 4 + 2] - bf2f(h2));
        unsigned short e3 = f2bf(p[qs][ks * 4 + 3] - bf2f(h3));
        u32x2 wh, wl;
        wh[0] = (unsigned)h0 | ((unsigned)h1 << 16);
        wh[1] = (unsigned)h2 | ((unsigned)h3 << 16);
        wl[0] = (unsigned)e0 | ((unsigned)e1 << 16);
        wl[1] = (unsigned)e2 | ((unsigned)e3 << 16);
        const int ko2 = (ks * 32 + 8 * g) ^ sw;
        *(u32x2*)(PhB + row * 128 + ko2) = wh;
        *(u32x2*)(PlB + row * 128 + ko2) = wl;
      }
    }
    // ---- O^T += V^T * P^T (3-term split) ----
    #pragma unroll
    for (int k2 = 0; k2 < 2; ++k2) {
      bf16x8 pbh[2], pbl[2];
      #pragma unroll
      for (int qs = 0; qs < 2; ++qs) {
        const int row = qs * 16 + lq;
        const int ko2 = (k2 * 64 + 16 * g) ^ sw;
        pbh[qs] = *(const bf16x8*)(PhB + row * 128 + ko2);
        pbl[qs] = *(const bf16x8*)(PlB + row * 128 + ko2);
      }
      #pragma unroll
      for (int ds = 0; ds < 2; ++ds) {
        const size_t vo = vbase + (size_t)(ds * 16 + lq) * NSEQ + key0 + k2 * 32 + 8 * g;
        bf16x8 vfh = *(const bf16x8*)(Vh + vo);
        bf16x8 vfl = *(const bf16x8*)(Vl + vo);
        #pragma unroll
        for (int qs = 0; qs < 2; ++qs) {
          acc[ds][qs] = __builtin_amdgcn_mfma_f32_16x16x32_bf16(vfh, pbh[qs], acc[ds][qs], 0, 0, 0);
          acc[ds][qs] = __builtin_amdgcn_mfma_f32_16x16x32_bf16(vfh, pbl[qs], acc[ds][qs], 0, 0, 0);
          acc[ds][qs] = __builtin_amdgcn_mfma_f32_16x16x32_bf16(vfl, pbh[qs], acc[ds][qs], 0, 0, 0);
        }
      }
    }
  }
  // ---- normalize + write O^T -> ao ----
  #pragma unroll
  for (int qs = 0; qs < 2; ++qs) {
    const float inv = 1.f / l_[qs];
    #pragma unroll
    for (int ds = 0; ds < 2; ++ds)
      #pragma unroll
      for (int r = 0; r < 4; ++r) {
        const int d = ds * 16 + 4 * g + r;
        ao[((size_t)b * 512 + h * 32 + d) * NSEQ + n0 + qs * 16 + lq] = acc[ds][qs][r] * inv;
      }
  }
}

// ---------------------------------------------------------------------------
extern "C" void kernel_launch(void* const* d_in, const int* in_sizes, int n_in,
                              void* d_out, int out_size, void* d_ws, size_t ws_size,
                              hipStream_t stream) {
  const float* x = (const float*)d_in[0];
  const float* qkv_w = (const float*)d_in[1];
  const float* qkv_b = (const float*)d_in[2];
  const float* out_w = (const float*)d_in[3];
  const float* out_b = (const float*)d_in[4];
  float* out = (float*)d_out;

  char* ws = (char*)d_ws;
  float* qkvf = (float*)ws;                                   // [2][512][4096] fp32 (Q,K) 16MB
  unsigned short* Khp = (unsigned short*)(ws + (16u << 20));  // [16][4096][32] 4MB
  unsigned short* Klp = (unsigned short*)(ws + (20u << 20));  // 4MB
  unsigned short* Vhp = (unsigned short*)(ws + (24u << 20));  // [16][32][4096] 4MB
  unsigned short* Vlp = (unsigned short*)(ws + (28u << 20));  // 4MB

  // QKV projection: Q,K fp32 into qkvf; V split directly to bf16 planes.
  gemm_bias<<<dim3(NSEQ / 64, 768 / 64, 2), 256, 0, stream>>>(
      qkv_w, x, qkv_b, qkvf, 768, 256, NSEQ, (size_t)256 * NSEQ, 512, Vhp, Vlp);
  // K transpose-split to [bh][n][d] planes.
  prep_k<<<dim3(NSEQ / 64, 16, 1), 256, 0, stream>>>(qkvf, Khp, Klp);
  // Attention; ao aliases the (consumed) Q region of qkvf.
  attn_mfma<<<dim3(NSEQ / 128, 8, 2), 256, 0, stream>>>(qkvf, Khp, Klp, Vhp, Vlp, qkvf);
  // Output projection reads ao (qkvf channels 0..255, b-stride 512*N).
  gemm_bias<<<dim3(NSEQ / 64, 256 / 64, 2), 256, 0, stream>>>(
      out_w, qkvf, out_b, out, 256, 256, NSEQ, (size_t)512 * NSEQ, 256, nullptr, nullptr);
}

// Round 4
// 171.286 us; speedup vs baseline: 7.8303x; 2.0488x over previous
//
#include <hip/hip_runtime.h>
#include <math.h>

#define NSEQ 4096
#define QSC (0.17677669529663687f * 1.4426950408889634f)  // 32^-0.5 * log2(e)

typedef __attribute__((ext_vector_type(2))) _Float16 half2v;
typedef __attribute__((ext_vector_type(8))) _Float16 half8;
typedef __attribute__((ext_vector_type(4))) float f32x4;
typedef __attribute__((ext_vector_type(2))) unsigned int u32x2;

#if __has_builtin(__builtin_amdgcn_exp2f)
#define EXP2(x) __builtin_amdgcn_exp2f(x)
#else
#define EXP2(x) exp2f(x)
#endif

__device__ __forceinline__ half2v pk2(float a, float b) {
  return __builtin_bit_cast(half2v, __builtin_amdgcn_cvt_pkrtz(a, b));
}

// ---------------------------------------------------------------------------
// Y[b][m][n] = sum_k W[m][k] * X[b][k][n] + bias[m]   (fp32 VALU tile GEMM)
// If Vh != nullptr and m0 >= 512: rows are V channels -> write fp16 plane
// [bh][d][n] instead of fp32 Y.
// ---------------------------------------------------------------------------
__global__ __launch_bounds__(256) void gemm_bias(
    const float* __restrict__ W, const float* __restrict__ X,
    const float* __restrict__ bias, float* __restrict__ Y,
    int M, int K, int N, size_t xbstride, int ybstride,
    _Float16* __restrict__ Vh) {
  __shared__ float As[64][68];  // [k][m]
  __shared__ float Bs[64][68];  // [k][n]
  const int b = blockIdx.z;
  const int n0 = blockIdx.x * 64, m0 = blockIdx.y * 64;
  const float* Xb = X + (size_t)b * xbstride;
  const int tid = threadIdx.x;
  const int tx = tid & 15, ty = tid >> 4;
  float acc[4][4] = {};
  for (int k0 = 0; k0 < K; k0 += 64) {
    #pragma unroll
    for (int i = 0; i < 4; ++i) {
      const int r = ty + 16 * i;
      float4 w4 = *(const float4*)(W + (size_t)(m0 + r) * K + k0 + tx * 4);
      As[tx * 4 + 0][r] = w4.x;
      As[tx * 4 + 1][r] = w4.y;
      As[tx * 4 + 2][r] = w4.z;
      As[tx * 4 + 3][r] = w4.w;
      float4 x4 = *(const float4*)(Xb + (size_t)(k0 + r) * N + n0 + tx * 4);
      *(float4*)&Bs[r][tx * 4] = x4;
    }
    __syncthreads();
    #pragma unroll 8
    for (int kk = 0; kk < 64; ++kk) {
      float4 a4 = *(const float4*)&As[kk][ty * 4];
      float4 b4 = *(const float4*)&Bs[kk][tx * 4];
      const float av[4] = {a4.x, a4.y, a4.z, a4.w};
      const float bv[4] = {b4.x, b4.y, b4.z, b4.w};
      #pragma unroll
      for (int i = 0; i < 4; ++i)
        #pragma unroll
        for (int jj = 0; jj < 4; ++jj)
          acc[i][jj] = fmaf(av[i], bv[jj], acc[i][jj]);
    }
    __syncthreads();
  }
  if (Vh != nullptr && m0 >= 512) {
    #pragma unroll
    for (int i = 0; i < 4; ++i) {
      const int o = m0 + ty * 4 + i;
      const float bi = bias[o];
      const int d = o & 31, hh = (o >> 5) - 16;
      half2v p0 = pk2(acc[i][0] + bi, acc[i][1] + bi);
      half2v p1 = pk2(acc[i][2] + bi, acc[i][3] + bi);
      u32x2 wv;
      wv[0] = __builtin_bit_cast(unsigned, p0);
      wv[1] = __builtin_bit_cast(unsigned, p1);
      *(u32x2*)(Vh + (((size_t)(b * 8 + hh)) * 32 + d) * N + n0 + tx * 4) = wv;
    }
  } else {
    #pragma unroll
    for (int i = 0; i < 4; ++i) {
      const float bi = bias[m0 + ty * 4 + i];
      float4 o;
      o.x = acc[i][0] + bi;
      o.y = acc[i][1] + bi;
      o.z = acc[i][2] + bi;
      o.w = acc[i][3] + bi;
      *(float4*)(Y + ((size_t)b * ybstride + m0 + ty * 4 + i) * N + n0 + tx * 4) = o;
    }
  }
}

// ---------------------------------------------------------------------------
// Q/K prep: transpose fp32 qkv channels [b][c][n] -> fp16 planes [bh][n][32d].
// Q (blockIdx.y < 16) is also scaled by QSC. grid (N/64, 32), 256 thr.
// ---------------------------------------------------------------------------
__global__ __launch_bounds__(256) void prep_qk(
    const float* __restrict__ qkvf, _Float16* __restrict__ Qh,
    _Float16* __restrict__ Kh) {
  const int z = blockIdx.y;
  const int isq = (z < 16) ? 1 : 0;
  const int bh = z & 15, b = bh >> 3, hh = bh & 7;
  const int n0 = blockIdx.x * 64;
  const int t = threadIdx.x;
  const int n = t >> 2, dg = t & 3;
  const float sc = isq ? QSC : 1.0f;
  const float* src =
      qkvf + ((size_t)b * 512 + (isq ? 0 : 256) + hh * 32 + 8 * dg) * NSEQ + n0 + n;
  float v[8];
  #pragma unroll
  for (int i = 0; i < 8; ++i) v[i] = src[(size_t)i * NSEQ] * sc;
  half8 out;
  #pragma unroll
  for (int i = 0; i < 4; ++i) {
    half2v p = pk2(v[2 * i], v[2 * i + 1]);
    out[2 * i] = p[0];
    out[2 * i + 1] = p[1];
  }
  _Float16* dst = (isq ? Qh : Kh) + ((size_t)bh * NSEQ + n0 + n) * 32 + 8 * dg;
  *(half8*)dst = out;
}

// ---------------------------------------------------------------------------
// MFMA flash attention, fp16 single-plane.
// Q,K planes [bh][n][32d] (Q pre-scaled by QSC); V plane [bh][32d][n].
// Swapped QK: S^T = K*Q^T (softmax = 2 shfl_xor); PV as O^T = V^T * P^T with
// P through a wave-private XOR-swizzled LDS tile. Defer-rescale (thr=8).
// 4 waves x 32 queries = 128 q/block. ao: [b][512 rows][n], rows 0..255 used.
// ---------------------------------------------------------------------------
__global__ __launch_bounds__(256) void attn_mfma(
    const _Float16* __restrict__ Qh, const _Float16* __restrict__ Kh,
    const _Float16* __restrict__ Vh, float* __restrict__ ao) {
  __shared__ _Float16 P_lds[4][32][64];  // 16 KiB: [wave][q][k]
  const int b = blockIdx.z, h = blockIdx.y, bh = b * 8 + h;
  const int tid = threadIdx.x, w = tid >> 6, lane = tid & 63;
  const int lq = lane & 15, g = lane >> 4;
  const int n0 = blockIdx.x * 128 + w * 32;
  const int sw = (lq & 7) << 4;

  half8 qf[2];
  #pragma unroll
  for (int qs = 0; qs < 2; ++qs)
    qf[qs] = *(const half8*)(Qh + ((size_t)bh * NSEQ + n0 + qs * 16 + lq) * 32 + 8 * g);

  f32x4 acc[2][2] = {};
  float m_[2] = {-1e30f, -1e30f}, l_[2] = {0.f, 0.f};
  char* PB = (char*)&P_lds[w][0][0];
  const size_t kb = (size_t)bh * NSEQ * 32;
  const size_t vb = (size_t)bh * 32 * NSEQ;

  #pragma unroll 2
  for (int t = 0; t < NSEQ / 64; ++t) {
    const int key0 = t * 64;
    // ---- K tile loads + S^T = K * Q^T ----
    half8 kf[4];
    #pragma unroll
    for (int ks = 0; ks < 4; ++ks)
      kf[ks] = *(const half8*)(Kh + kb + (size_t)(key0 + ks * 16 + lq) * 32 + 8 * g);
    float p[2][16];
    #pragma unroll
    for (int ks = 0; ks < 4; ++ks)
      #pragma unroll
      for (int qs = 0; qs < 2; ++qs) {
        f32x4 c = {0.f, 0.f, 0.f, 0.f};
        c = __builtin_amdgcn_mfma_f32_16x16x32_f16(kf[ks], qf[qs], c, 0, 0, 0);
        #pragma unroll
        for (int r = 0; r < 4; ++r) p[qs][ks * 4 + r] = c[r];
      }
    // ---- online softmax (defer-rescale) + P -> LDS ----
    #pragma unroll
    for (int qs = 0; qs < 2; ++qs) {
      float mt = p[qs][0];
      #pragma unroll
      for (int i = 1; i < 16; ++i) mt = fmaxf(mt, p[qs][i]);
      mt = fmaxf(mt, __shfl_xor(mt, 16));
      mt = fmaxf(mt, __shfl_xor(mt, 32));
      if (!__all(mt <= m_[qs] + 8.f)) {
        const float mn = fmaxf(m_[qs], mt);
        const float rs = EXP2(m_[qs] - mn);
        m_[qs] = mn;
        l_[qs] *= rs;
        acc[0][qs] *= rs;
        acc[1][qs] *= rs;
      }
      float ps = 0.f;
      #pragma unroll
      for (int i = 0; i < 16; ++i) {
        p[qs][i] = EXP2(p[qs][i] - m_[qs]);
        ps += p[qs][i];
      }
      ps += __shfl_xor(ps, 16);
      ps += __shfl_xor(ps, 32);
      l_[qs] += ps;
      const int row = qs * 16 + lq;
      #pragma unroll
      for (int ks = 0; ks < 4; ++ks) {
        u32x2 wv;
        wv[0] = __builtin_bit_cast(unsigned, pk2(p[qs][ks * 4 + 0], p[qs][ks * 4 + 1]));
        wv[1] = __builtin_bit_cast(unsigned, pk2(p[qs][ks * 4 + 2], p[qs][ks * 4 + 3]));
        *(u32x2*)(PB + row * 128 + ((ks * 32 + 8 * g) ^ sw)) = wv;
      }
    }
    // ---- O^T += V^T * P^T ----
    #pragma unroll
    for (int k2 = 0; k2 < 2; ++k2) {
      half8 pb[2];
      #pragma unroll
      for (int qs = 0; qs < 2; ++qs)
        pb[qs] = *(const half8*)(PB + (qs * 16 + lq) * 128 + ((k2 * 64 + 16 * g) ^ sw));
      #pragma unroll
      for (int ds = 0; ds < 2; ++ds) {
        half8 vf = *(const half8*)(Vh + vb + (size_t)(ds * 16 + lq) * NSEQ + key0 +
                                   k2 * 32 + 8 * g);
        #pragma unroll
        for (int qs = 0; qs < 2; ++qs)
          acc[ds][qs] = __builtin_amdgcn_mfma_f32_16x16x32_f16(vf, pb[qs], acc[ds][qs], 0, 0, 0);
      }
    }
  }
  // ---- normalize + write O^T -> ao ----
  #pragma unroll
  for (int qs = 0; qs < 2; ++qs) {
    const float inv = 1.f / l_[qs];
    #pragma unroll
    for (int ds = 0; ds < 2; ++ds)
      #pragma unroll
      for (int r = 0; r < 4; ++r) {
        const int d = ds * 16 + 4 * g + r;
        ao[((size_t)b * 512 + h * 32 + d) * NSEQ + n0 + qs * 16 + lq] = acc[ds][qs][r] * inv;
      }
  }
}

// ---------------------------------------------------------------------------
extern "C" void kernel_launch(void* const* d_in, const int* in_sizes, int n_in,
                              void* d_out, int out_size, void* d_ws, size_t ws_size,
                              hipStream_t stream) {
  const float* x = (const float*)d_in[0];
  const float* qkv_w = (const float*)d_in[1];
  const float* qkv_b = (const float*)d_in[2];
  const float* out_w = (const float*)d_in[3];
  const float* out_b = (const float*)d_in[4];
  float* out = (float*)d_out;

  char* ws = (char*)d_ws;
  float* qkvf = (float*)ws;                            // [2][512][4096] fp32 (Q,K) 16MB
  _Float16* Qhp = (_Float16*)(ws + (16u << 20));       // [16][4096][32] 4MB
  _Float16* Khp = (_Float16*)(ws + (20u << 20));       // [16][4096][32] 4MB
  _Float16* Vhp = (_Float16*)(ws + (24u << 20));       // [16][32][4096] 4MB

  // QKV projection: Q,K fp32 into qkvf; V straight to fp16 plane.
  gemm_bias<<<dim3(NSEQ / 64, 768 / 64, 2), 256, 0, stream>>>(
      qkv_w, x, qkv_b, qkvf, 768, 256, NSEQ, (size_t)256 * NSEQ, 512, Vhp);
  // Q (scaled) and K transpose to fp16 [bh][n][d] planes.
  prep_qk<<<dim3(NSEQ / 64, 32, 1), 256, 0, stream>>>(qkvf, Qhp, Khp);
  // Attention; ao aliases qkvf rows 0..255 (consumed fp32 Q region).
  attn_mfma<<<dim3(NSEQ / 128, 8, 2), 256, 0, stream>>>(Qhp, Khp, Vhp, qkvf);
  // Output projection reads ao (qkvf rows 0..255, b-stride 512*N).
  gemm_bias<<<dim3(NSEQ / 64, 256 / 64, 2), 256, 0, stream>>>(
      out_w, qkvf, out_b, out, 256, 256, NSEQ, (size_t)512 * NSEQ, 256, nullptr);
}